// Round 13
// baseline (364.417 us; speedup 1.0000x reference)
//
#include <hip/hip_runtime.h>
#include <hip/hip_bf16.h>

#define NROWS 32768
#define KCODES 8192
#define DDIM 128
#define TT 2048
#define ETOT 4194304  // 16*128*2048

typedef __attribute__((ext_vector_type(8))) _Float16 f16x8;
typedef __attribute__((ext_vector_type(4))) float f32x4;

// pack: (v & ~0x1FFF) | p, p in [0,8191] -> single v_and_or_b32.
__device__ __forceinline__ float pk(float v, int p) {
    return __int_as_float((__float_as_int(v) & 0xFFFFE000) | p);
}

__device__ __forceinline__ void async16(char* lds_uniform, const char* g_perlane) {
    __builtin_amdgcn_global_load_lds(
        (const __attribute__((address_space(1))) unsigned int*)g_perlane,
        (__attribute__((address_space(3))) unsigned int*)lds_uniform,
        16, 0, 0);
}

// ---------------------------------------------------------------------------
// k1: normalize codebook rows, fp32 -> fp16, MFMA A-fragment order per
//     16-code tile (4KB each).
// ---------------------------------------------------------------------------
__global__ void k_en_prep(const float* __restrict__ cb,
                          _Float16* __restrict__ eh) {
    int w = (blockIdx.x * blockDim.x + threadIdx.x) >> 6;  // code id
    int l = threadIdx.x & 63;
    if (w >= KCODES) return;
    const float* row = cb + (long)w * DDIM;
    float v0 = row[l], v1 = row[l + 64];
    float ss = v0 * v0 + v1 * v1;
#pragma unroll
    for (int s = 1; s < 64; s <<= 1) ss += __shfl_xor(ss, s, 64);
    float inv = 1.0f / fmaxf(sqrtf(ss), 1e-12f);
    int tile = w >> 4, c = w & 15;
#pragma unroll
    for (int e = 0; e < 2; e++) {
        int d = l + e * 64;
        float v = (e ? v1 : v0) * inv;
        int ks = d >> 5, kq = (d >> 3) & 3, dr = d & 7;
        long off = (long)tile * 2048 + ks * 512 + (kq * 16 + c) * 8 + dr;
        eh[off] = (_Float16)v;
    }
}

// ---------------------------------------------------------------------------
// k2: transpose inputs [B,D,T] -> xh [N=B*T, D] row-major fp16.
// ---------------------------------------------------------------------------
__global__ void k_x_prep(const float* __restrict__ in,
                         _Float16* __restrict__ xh) {
    __shared__ float tb[64][65];
    int bid = blockIdx.x;
    int tt0 = (bid & 31) * 64;
    int dd0 = ((bid >> 5) & 1) * 64;
    int b = bid >> 6;
    const float* base = in + (long)b * DDIM * TT;
    int tl = threadIdx.x & 63;
    int dg = threadIdx.x >> 6;
#pragma unroll
    for (int i = 0; i < 16; i++) {
        int dd = dg + i * 4;
        tb[dd][tl] = base[(long)(dd0 + dd) * TT + tt0 + tl];
    }
    __syncthreads();
    int dl = threadIdx.x & 63;
    int tg = threadIdx.x >> 6;
#pragma unroll
    for (int i = 0; i < 16; i++) {
        int t = tg + i * 4;
        long n = (long)b * TT + tt0 + t;
        xh[n * DDIM + dd0 + dl] = (_Float16)tb[dl][t];
    }
}

// ---------------------------------------------------------------------------
// k3 v12 (PRODUCTION, byte-identical to r12): shared staging, 1024 blocks
// x 256 thr, triple-buffered, counted vmcnt + barrier, top-2/eighth.
// ---------------------------------------------------------------------------
__global__ __launch_bounds__(256, 4) void k_main(const _Float16* __restrict__ xh,
                                                 const _Float16* __restrict__ eh,
                                                 int* __restrict__ cand) {
    extern __shared__ char lds[];
    const int tid = threadIdx.x;
    const int l = tid & 63;
    const int w = tid >> 6;
    const int e8 = blockIdx.x & 7;
    const int rb = blockIdx.x >> 3;
    const int col = l & 15, kq = l >> 4;
    const long rbase = (long)rb * 256;

    f16x8 bx[4][4];
#pragma unroll
    for (int nf = 0; nf < 4; nf++) {
        long n = rbase + w * 64 + nf * 16 + col;
#pragma unroll
        for (int ks = 0; ks < 4; ks++)
            bx[nf][ks] = *(const f16x8*)(xh + n * DDIM + ks * 32 + kq * 8);
    }

    const float NEG = __int_as_float(0xFF800000);
    const f32x4 Z = {0.f, 0.f, 0.f, 0.f};
    float t1[4], t2[4], t3[4], u1[4];
#pragma unroll
    for (int i = 0; i < 4; i++) { t1[i] = t2[i] = t3[i] = u1[i] = NEG; }

    int P = 8191 - (e8 * 1024 + kq * 4);

    const char* gsrc = (const char*)eh + (long)e8 * 262144 + w * 1024 + l * 16;
    char* b0 = lds;
    char* b1 = lds + 4096;
    char* b2 = lds + 8192;

    async16(b0 + w * 1024, gsrc);
    async16(b1 + w * 1024, gsrc + 4096);

    for (int t = 0; t < 64; ++t) {
        if (t < 62) {
            asm volatile("s_waitcnt vmcnt(1) lgkmcnt(0)\n\ts_barrier" ::: "memory");
            async16(b2 + w * 1024, gsrc + (t + 2) * 4096);
        } else if (t == 62) {
            asm volatile("s_waitcnt vmcnt(1) lgkmcnt(0)\n\ts_barrier" ::: "memory");
        } else {
            asm volatile("s_waitcnt vmcnt(0) lgkmcnt(0)\n\ts_barrier" ::: "memory");
        }

        f16x8 ah[4];
#pragma unroll
        for (int ks = 0; ks < 4; ks++)
            ah[ks] = *(const f16x8*)(b0 + ks * 1024 + l * 16);

        __builtin_amdgcn_s_setprio(1);
        f32x4 acc[4];
#pragma unroll
        for (int nf = 0; nf < 4; nf++) {
            f32x4 a = __builtin_amdgcn_mfma_f32_16x16x32_f16(ah[0], bx[nf][0], Z, 0, 0, 0);
            a = __builtin_amdgcn_mfma_f32_16x16x32_f16(ah[1], bx[nf][1], a, 0, 0, 0);
            a = __builtin_amdgcn_mfma_f32_16x16x32_f16(ah[2], bx[nf][2], a, 0, 0, 0);
            acc[nf] = __builtin_amdgcn_mfma_f32_16x16x32_f16(ah[3], bx[nf][3], a, 0, 0, 0);
        }
        __builtin_amdgcn_s_setprio(0);

#pragma unroll
        for (int nf = 0; nf < 4; nf++) {
            f32x4 a = acc[nf];
            float s0 = pk(a[0], P),     s1 = pk(a[1], P - 1);
            float s2 = pk(a[2], P - 2), s3 = pk(a[3], P - 3);
            float h01 = fmaxf(s0, s1), l01 = fminf(s0, s1);
            float h23 = fmaxf(s2, s3), l23 = fminf(s2, s3);
            float m1 = fmaxf(h01, h23);
            float m2 = fmaxf(fminf(h01, h23), fmaxf(l01, l23));
            float n1 = fminf(t1[nf], m1); t1[nf] = fmaxf(t1[nf], m1);
            float n2 = fminf(t2[nf], n1); t2[nf] = fmaxf(t2[nf], n1);
            t3[nf] = fmaxf(t3[nf], n2);
            u1[nf] = fmaxf(u1[nf], m2);
        }
        P -= 16;

        char* tmp = b0; b0 = b1; b1 = b2; b2 = tmp;
    }

    float* mrg = (float*)(lds + 12288);  // [256 rows][17]
#pragma unroll
    for (int nf = 0; nf < 4; nf++) {
        int row = w * 64 + nf * 16 + col;
        int e = kq * 4;
        mrg[row * 17 + e + 0] = t1[nf];
        mrg[row * 17 + e + 1] = t2[nf];
        mrg[row * 17 + e + 2] = t3[nf];
        mrg[row * 17 + e + 3] = u1[nf];
    }
    __syncthreads();
    {
        float s1 = NEG, s2 = NEG;
#pragma unroll 4
        for (int e = 0; e < 16; e++) {
            float v = mrg[tid * 17 + e];
            float a1 = fminf(s1, v); s1 = fmaxf(s1, v);
            s2 = fmaxf(s2, a1);
        }
        long n = rbase + tid;
        int* cp = cand + n * 16 + e8 * 2;
        cp[0] = 8191 - (__float_as_int(s1) & 0x1FFF);
        cp[1] = 8191 - (__float_as_int(s2) & 0x1FFF);
    }
}

// ---------------------------------------------------------------------------
// ABLATION V1: k_main minus selection (per-tile keep-alive on acc).
// Writes nothing. Duration isolates in-situ selection cost.
// ---------------------------------------------------------------------------
__global__ __launch_bounds__(256, 4) void k_abl_nosel(const _Float16* __restrict__ xh,
                                                      const _Float16* __restrict__ eh) {
    extern __shared__ char lds[];
    const int tid = threadIdx.x;
    const int l = tid & 63;
    const int w = tid >> 6;
    const int e8 = blockIdx.x & 7;
    const int rb = blockIdx.x >> 3;
    const int col = l & 15, kq = l >> 4;
    const long rbase = (long)rb * 256;

    f16x8 bx[4][4];
#pragma unroll
    for (int nf = 0; nf < 4; nf++) {
        long n = rbase + w * 64 + nf * 16 + col;
#pragma unroll
        for (int ks = 0; ks < 4; ks++)
            bx[nf][ks] = *(const f16x8*)(xh + n * DDIM + ks * 32 + kq * 8);
    }

    const f32x4 Z = {0.f, 0.f, 0.f, 0.f};
    const char* gsrc = (const char*)eh + (long)e8 * 262144 + w * 1024 + l * 16;
    char* b0 = lds;
    char* b1 = lds + 4096;
    char* b2 = lds + 8192;

    async16(b0 + w * 1024, gsrc);
    async16(b1 + w * 1024, gsrc + 4096);

    for (int t = 0; t < 64; ++t) {
        if (t < 62) {
            asm volatile("s_waitcnt vmcnt(1) lgkmcnt(0)\n\ts_barrier" ::: "memory");
            async16(b2 + w * 1024, gsrc + (t + 2) * 4096);
        } else if (t == 62) {
            asm volatile("s_waitcnt vmcnt(1) lgkmcnt(0)\n\ts_barrier" ::: "memory");
        } else {
            asm volatile("s_waitcnt vmcnt(0) lgkmcnt(0)\n\ts_barrier" ::: "memory");
        }

        f16x8 ah[4];
#pragma unroll
        for (int ks = 0; ks < 4; ks++)
            ah[ks] = *(const f16x8*)(b0 + ks * 1024 + l * 16);

        __builtin_amdgcn_s_setprio(1);
        f32x4 acc[4];
#pragma unroll
        for (int nf = 0; nf < 4; nf++) {
            f32x4 a = __builtin_amdgcn_mfma_f32_16x16x32_f16(ah[0], bx[nf][0], Z, 0, 0, 0);
            a = __builtin_amdgcn_mfma_f32_16x16x32_f16(ah[1], bx[nf][1], a, 0, 0, 0);
            a = __builtin_amdgcn_mfma_f32_16x16x32_f16(ah[2], bx[nf][2], a, 0, 0, 0);
            acc[nf] = __builtin_amdgcn_mfma_f32_16x16x32_f16(ah[3], bx[nf][3], a, 0, 0, 0);
        }
        __builtin_amdgcn_s_setprio(0);

        // keep-alive: forces per-tile MFMA without selection (rule #17)
#pragma unroll
        for (int nf = 0; nf < 4; nf++)
            asm volatile("" :: "v"(acc[nf][0]), "v"(acc[nf][1]),
                              "v"(acc[nf][2]), "v"(acc[nf][3]));

        char* tmp = b0; b0 = b1; b1 = b2; b2 = tmp;
    }
}

// ---------------------------------------------------------------------------
// ABLATION V4 (4x iterations so it TOPS the rocprof chart -> directly
// readable): pure register-fed MFMA, same chain structure, no LDS/no sel.
// Anti-hoist: per-tile f16 bump into ah[0][0] (all 16 MFMAs chain off it).
// Per-1x floor = shown/4. Writes nothing.
// ---------------------------------------------------------------------------
__global__ __launch_bounds__(256, 4) void k_abl_mfma4x(const _Float16* __restrict__ xh) {
    extern __shared__ char lds[];  // allocated (29696) for occupancy parity; unused
    const int tid = threadIdx.x;
    const int l = tid & 63;
    const int w = tid >> 6;
    const int col = l & 15, kq = l >> 4;
    const long rbase = (long)(blockIdx.x >> 3) * 256;

    f16x8 bx[4][4];
#pragma unroll
    for (int nf = 0; nf < 4; nf++) {
        long n = rbase + w * 64 + nf * 16 + col;
#pragma unroll
        for (int ks = 0; ks < 4; ks++)
            bx[nf][ks] = *(const f16x8*)(xh + n * DDIM + ks * 32 + kq * 8);
    }
    f16x8 ah[4];
#pragma unroll
    for (int ks = 0; ks < 4; ks++) ah[ks] = bx[ks][ks];

    const f32x4 Z = {0.f, 0.f, 0.f, 0.f};
    _Float16 bump = (_Float16)0.0f;

    for (int t = 0; t < 256; ++t) {   // 4x the production 64 tiles
        bump += (_Float16)1.0f;
        ah[0][0] = bump;              // per-tile variance -> no hoist/CSE

        __builtin_amdgcn_s_setprio(1);
        f32x4 acc[4];
#pragma unroll
        for (int nf = 0; nf < 4; nf++) {
            f32x4 a = __builtin_amdgcn_mfma_f32_16x16x32_f16(ah[0], bx[nf][0], Z, 0, 0, 0);
            a = __builtin_amdgcn_mfma_f32_16x16x32_f16(ah[1], bx[nf][1], a, 0, 0, 0);
            a = __builtin_amdgcn_mfma_f32_16x16x32_f16(ah[2], bx[nf][2], a, 0, 0, 0);
            acc[nf] = __builtin_amdgcn_mfma_f32_16x16x32_f16(ah[3], bx[nf][3], a, 0, 0, 0);
        }
        __builtin_amdgcn_s_setprio(0);
#pragma unroll
        for (int nf = 0; nf < 4; nf++)
            asm volatile("" :: "v"(acc[nf][0]), "v"(acc[nf][1]),
                              "v"(acc[nf][2]), "v"(acc[nf][3]));
    }
}

// ---------------------------------------------------------------------------
// k4 v4: lane-per-(row,candidate) fp64 refine (unchanged).
// ---------------------------------------------------------------------------
__global__ void k_refine16(const float* __restrict__ in, const float* __restrict__ cb,
                           const int* __restrict__ cand, int* __restrict__ idx_out,
                           float* __restrict__ idx_f) {
    int g = blockIdx.x * blockDim.x + threadIdx.x;
    int n = g >> 4, k = g & 15;
    int b = n >> 11, t = n & 2047;
    const float* xb = in + (long)b * DDIM * TT + t;
    int c = cand[n * 16 + k];
    const float4* e = (const float4*)(cb + (long)c * DDIM);
    double dot = 0.0, nrm = 0.0;
    for (int d4 = 0; d4 < 32; d4++) {
        float4 q = e[d4];
#pragma unroll
        for (int j = 0; j < 4; j++) {
            double xd = (double)xb[(long)(d4 * 4 + j) * TT];
            double f = (double)((const float*)&q)[j];
            dot += xd * f;
            nrm += f * f;
        }
    }
    double sv = dot / fmax(sqrt(nrm), 1e-12);
#pragma unroll
    for (int s = 1; s < 16; s <<= 1) {
        double osv = __shfl_xor(sv, s, 64);
        int oc = __shfl_xor(c, s, 64);
        if (osv > sv || (osv == sv && oc < c)) { sv = osv; c = oc; }
    }
    if (k == 0) {
        idx_out[n] = c;
        idx_f[n] = (float)c;
    }
}

// ---------------------------------------------------------------------------
// k5: out = x + (q - x) + fp64 loss partials (unchanged).
// ---------------------------------------------------------------------------
__global__ void k_out_loss(const float* __restrict__ in, const float* __restrict__ cb,
                           const int* __restrict__ idx, float* __restrict__ out,
                           double* __restrict__ part) {
    __shared__ double sd[256];
    double acc = 0.0;
    for (long e = (long)blockIdx.x * blockDim.x + threadIdx.x; e < ETOT;
         e += (long)gridDim.x * blockDim.x) {
        long t = e & 2047;
        long d = (e >> 11) & 127;
        long b = e >> 18;
        float xv = in[e];
        int n = (int)((b << 11) | t);
        float qv = cb[(long)idx[n] * DDIM + d];
        float diff = qv - xv;
        out[e] = xv + diff;
        acc += (double)diff * (double)diff;
    }
    sd[threadIdx.x] = acc;
    __syncthreads();
    for (int s = 128; s > 0; s >>= 1) {
        if (threadIdx.x < s) sd[threadIdx.x] += sd[threadIdx.x + s];
        __syncthreads();
    }
    if (threadIdx.x == 0) part[blockIdx.x] = sd[0];
}

__global__ void k_loss_final(const double* __restrict__ part, int np,
                             float* __restrict__ loss) {
    __shared__ double sd[256];
    double a = 0.0;
    for (int i = threadIdx.x; i < np; i += 256) a += part[i];
    sd[threadIdx.x] = a;
    __syncthreads();
    for (int s = 128; s > 0; s >>= 1) {
        if (threadIdx.x < s) sd[threadIdx.x] += sd[threadIdx.x + s];
        __syncthreads();
    }
    if (threadIdx.x == 0) {
        float m = (float)(sd[0] / (double)ETOT);
        loss[0] = m + 0.02f * m;
    }
}

// ---------------------------------------------------------------------------
extern "C" void kernel_launch(void* const* d_in, const int* in_sizes, int n_in,
                              void* d_out, int out_size, void* d_ws, size_t ws_size,
                              hipStream_t stream) {
    const float* inputs = (const float*)d_in[0];   // [16,128,2048] fp32
    const float* cb     = (const float*)d_in[1];   // [8192,128]    fp32
    float* outf = (float*)d_out;                   // [loss | out(B,D,T) | idx]

    char* ws = (char*)d_ws;
    _Float16* xh = (_Float16*)ws; ws += (long)NROWS * DDIM * 2;
    _Float16* eh = (_Float16*)ws; ws += (long)KCODES * DDIM * 2;
    int* cand    = (int*)ws;      ws += (long)NROWS * 16 * 4;
    int* idx     = (int*)ws;      ws += (long)NROWS * 4;
    double* part = (double*)ws;   ws += 2048 * 8;

    // --- production pipeline (identical to r12) ---
    k_en_prep<<<dim3(2048), dim3(256), 0, stream>>>(cb, eh);
    k_x_prep<<<dim3(1024), dim3(256), 0, stream>>>(inputs, xh);
    k_main<<<dim3(1024), dim3(256), 29696, stream>>>(xh, eh, cand);
    k_refine16<<<dim3(2048), dim3(256), 0, stream>>>(inputs, cb, cand, idx,
                                                     outf + 1 + (long)ETOT);
    k_out_loss<<<dim3(2048), dim3(256), 0, stream>>>(inputs, cb, idx, outf + 1, part);
    k_loss_final<<<dim3(1), dim3(256), 0, stream>>>(part, 2048, outf);

    // --- diagnostics (write nothing; durations decode the k_main wall) ---
    k_abl_nosel<<<dim3(1024), dim3(256), 29696, stream>>>(xh, eh);
    k_abl_mfma4x<<<dim3(1024), dim3(256), 29696, stream>>>(xh);
}

// Round 14
// 187.680 us; speedup vs baseline: 1.9417x; 1.9417x over previous
//
#include <hip/hip_runtime.h>
#include <hip/hip_bf16.h>

#define NROWS 32768
#define KCODES 8192
#define DDIM 128
#define TT 2048
#define ETOT 4194304  // 16*128*2048

typedef __attribute__((ext_vector_type(8))) _Float16 f16x8;
typedef __attribute__((ext_vector_type(4))) float f32x4;

// pack: (v & ~0x1FFF) | p, p in [0,8191] -> single v_and_or_b32.
__device__ __forceinline__ float pk(float v, int p) {
    return __int_as_float((__float_as_int(v) & 0xFFFFE000) | p);
}

__device__ __forceinline__ void async16(char* lds_uniform, const char* g_perlane) {
    __builtin_amdgcn_global_load_lds(
        (const __attribute__((address_space(1))) unsigned int*)g_perlane,
        (__attribute__((address_space(3))) unsigned int*)lds_uniform,
        16, 0, 0);
}

#define SYNC_MAIN asm volatile("s_waitcnt vmcnt(1) lgkmcnt(0)\n\ts_barrier" ::: "memory")
#define SYNC_LAST asm volatile("s_waitcnt vmcnt(0) lgkmcnt(0)\n\ts_barrier" ::: "memory")

// ---------------------------------------------------------------------------
// k1: normalize codebook rows, fp32 -> fp16, MFMA A-fragment order per
//     16-code tile (4KB each).
// ---------------------------------------------------------------------------
__global__ void k_en_prep(const float* __restrict__ cb,
                          _Float16* __restrict__ eh) {
    int w = (blockIdx.x * blockDim.x + threadIdx.x) >> 6;  // code id
    int l = threadIdx.x & 63;
    if (w >= KCODES) return;
    const float* row = cb + (long)w * DDIM;
    float v0 = row[l], v1 = row[l + 64];
    float ss = v0 * v0 + v1 * v1;
#pragma unroll
    for (int s = 1; s < 64; s <<= 1) ss += __shfl_xor(ss, s, 64);
    float inv = 1.0f / fmaxf(sqrtf(ss), 1e-12f);
    int tile = w >> 4, c = w & 15;
#pragma unroll
    for (int e = 0; e < 2; e++) {
        int d = l + e * 64;
        float v = (e ? v1 : v0) * inv;
        int ks = d >> 5, kq = (d >> 3) & 3, dr = d & 7;
        long off = (long)tile * 2048 + ks * 512 + (kq * 16 + c) * 8 + dr;
        eh[off] = (_Float16)v;
    }
}

// ---------------------------------------------------------------------------
// k2: transpose inputs [B,D,T] -> xh [N=B*T, D] row-major fp16.
// ---------------------------------------------------------------------------
__global__ void k_x_prep(const float* __restrict__ in,
                         _Float16* __restrict__ xh) {
    __shared__ float tb[64][65];
    int bid = blockIdx.x;
    int tt0 = (bid & 31) * 64;
    int dd0 = ((bid >> 5) & 1) * 64;
    int b = bid >> 6;
    const float* base = in + (long)b * DDIM * TT;
    int tl = threadIdx.x & 63;
    int dg = threadIdx.x >> 6;
#pragma unroll
    for (int i = 0; i < 16; i++) {
        int dd = dg + i * 4;
        tb[dd][tl] = base[(long)(dd0 + dd) * TT + tt0 + tl];
    }
    __syncthreads();
    int dl = threadIdx.x & 63;
    int tg = threadIdx.x >> 6;
#pragma unroll
    for (int i = 0; i < 16; i++) {
        int t = tg + i * 4;
        long n = (long)b * TT + tt0 + t;
        xh[n * DDIM + dd0 + dl] = (_Float16)tb[dl][t];
    }
}

// ---------------------------------------------------------------------------
// helpers for k_main's 2-phase pipeline (static acc naming, rule #20)
// ---------------------------------------------------------------------------
__device__ __forceinline__ void mfma4(const char* buf, int l,
                                      const f16x8 (&bx)[4][4], f32x4 (&acc)[4]) {
    const f32x4 Z = {0.f, 0.f, 0.f, 0.f};
    f16x8 ah[4];
#pragma unroll
    for (int ks = 0; ks < 4; ks++)
        ah[ks] = *(const f16x8*)(buf + ks * 1024 + l * 16);
    __builtin_amdgcn_s_setprio(1);
#pragma unroll
    for (int nf = 0; nf < 4; nf++) {
        f32x4 a = __builtin_amdgcn_mfma_f32_16x16x32_f16(ah[0], bx[nf][0], Z, 0, 0, 0);
        a = __builtin_amdgcn_mfma_f32_16x16x32_f16(ah[1], bx[nf][1], a, 0, 0, 0);
        a = __builtin_amdgcn_mfma_f32_16x16x32_f16(ah[2], bx[nf][2], a, 0, 0, 0);
        acc[nf] = __builtin_amdgcn_mfma_f32_16x16x32_f16(ah[3], bx[nf][3], a, 0, 0, 0);
    }
    __builtin_amdgcn_s_setprio(0);
}

// {t1,t2,u1}: exact top-2 per stream (t3 dropped -- cross-quad top-2 via
// t1/t2, same-quad 2nd via u1; 16-cand fp64 refine unchanged).
__device__ __forceinline__ void sel4(const f32x4 (&acc)[4], int PP,
                                     float (&t1)[4], float (&t2)[4], float (&u1)[4]) {
#pragma unroll
    for (int nf = 0; nf < 4; nf++) {
        f32x4 a = acc[nf];
        float s0 = pk(a[0], PP),     s1 = pk(a[1], PP - 1);
        float s2 = pk(a[2], PP - 2), s3 = pk(a[3], PP - 3);
        float h01 = fmaxf(s0, s1), l01 = fminf(s0, s1);
        float h23 = fmaxf(s2, s3), l23 = fminf(s2, s3);
        float m1 = fmaxf(h01, h23);                          // quad max
        float m2 = fmaxf(fminf(h01, h23), fmaxf(l01, l23));  // quad 2nd
        float n1 = fminf(t1[nf], m1); t1[nf] = fmaxf(t1[nf], m1);
        t2[nf] = fmaxf(t2[nf], n1);
        u1[nf] = fmaxf(u1[nf], m2);
    }
}

// ---------------------------------------------------------------------------
// k3 v13: r12 skeleton + acc DOUBLE-PIPELINE. Ablation (r13) showed:
// pure MFMA 39us, +staging 42us, +selection 96us -- the 54us is sel's
// dependency stall on the in-flight MFMA chain (all 4 waves barrier-locked).
// Fix: MFMA(t)->accB issues, then sel(accA = tile t-1) fills the MFMA
// shadow with no dependency. Explicit 2-phase loop, named accA/accB.
// ---------------------------------------------------------------------------
__global__ __launch_bounds__(256, 4) void k_main(const _Float16* __restrict__ xh,
                                                 const _Float16* __restrict__ eh,
                                                 int* __restrict__ cand) {
    extern __shared__ char lds[];
    const int tid = threadIdx.x;
    const int l = tid & 63;
    const int w = tid >> 6;
    const int e8 = blockIdx.x & 7;
    const int rb = blockIdx.x >> 3;
    const int col = l & 15, kq = l >> 4;
    const long rbase = (long)rb * 256;

    f16x8 bx[4][4];
#pragma unroll
    for (int nf = 0; nf < 4; nf++) {
        long n = rbase + w * 64 + nf * 16 + col;
#pragma unroll
        for (int ks = 0; ks < 4; ks++)
            bx[nf][ks] = *(const f16x8*)(xh + n * DDIM + ks * 32 + kq * 8);
    }

    const float NEG = __int_as_float(0xFF800000);
    float t1[4], t2[4], u1[4];
#pragma unroll
    for (int i = 0; i < 4; i++) { t1[i] = t2[i] = u1[i] = NEG; }

    int P = 8191 - (e8 * 1024 + kq * 4);

    const char* gsrc = (const char*)eh + (long)e8 * 262144 + w * 1024 + l * 16;
    char* b0 = lds;
    char* b1 = lds + 4096;
    char* b2 = lds + 8192;

    // prologue: stage tiles 0,1; tile 0 -> accA
    async16(b0 + w * 1024, gsrc);
    async16(b1 + w * 1024, gsrc + 4096);

    f32x4 accA[4], accB[4];
    int PA, PB;

    SYNC_MAIN;                                   // tile 0 landed (1 in flight)
    async16(b2 + w * 1024, gsrc + 2 * 4096);     // stage tile 2
    mfma4(b0, l, bx, accA); PA = P; P -= 16;
    { char* tp = b0; b0 = b1; b1 = b2; b2 = tp; }

    for (int u = 0; u < 31; ++u) {
        // tile 2u+1 -> accB ; sel(accA) in its MFMA shadow
        SYNC_MAIN;
        async16(b2 + w * 1024, gsrc + (2 * u + 3) * 4096);
        mfma4(b0, l, bx, accB); PB = P; P -= 16;
        sel4(accA, PA, t1, t2, u1);
        { char* tp = b0; b0 = b1; b1 = b2; b2 = tp; }

        // tile 2u+2 -> accA ; sel(accB)
        SYNC_MAIN;
        if (u != 30) async16(b2 + w * 1024, gsrc + (2 * u + 4) * 4096);
        mfma4(b0, l, bx, accA); PA = P; P -= 16;
        sel4(accB, PB, t1, t2, u1);
        { char* tp = b0; b0 = b1; b1 = b2; b2 = tp; }
    }
    // tile 63 -> accB ; drain
    SYNC_LAST;
    mfma4(b0, l, bx, accB); PB = P;
    sel4(accA, PA, t1, t2, u1);
    sel4(accB, PB, t1, t2, u1);

    // merge: 12 entries per row (4 kq x {t1,t2,u1}) -> top-2/eighth
    float* mrg = (float*)(lds + 12288);  // [256 rows][13]
#pragma unroll
    for (int nf = 0; nf < 4; nf++) {
        int row = w * 64 + nf * 16 + col;
        int e = kq * 3;
        mrg[row * 13 + e + 0] = t1[nf];
        mrg[row * 13 + e + 1] = t2[nf];
        mrg[row * 13 + e + 2] = u1[nf];
    }
    __syncthreads();
    {
        float s1 = NEG, s2 = NEG;
#pragma unroll 4
        for (int e = 0; e < 12; e++) {
            float v = mrg[tid * 13 + e];
            float a1 = fminf(s1, v); s1 = fmaxf(s1, v);
            s2 = fmaxf(s2, a1);
        }
        long n = rbase + tid;
        int* cp = cand + n * 16 + e8 * 2;
        cp[0] = 8191 - (__float_as_int(s1) & 0x1FFF);
        cp[1] = 8191 - (__float_as_int(s2) & 0x1FFF);
    }
}

// ---------------------------------------------------------------------------
// k4 v4: lane-per-(row,candidate) fp64 refine (unchanged).
// ---------------------------------------------------------------------------
__global__ void k_refine16(const float* __restrict__ in, const float* __restrict__ cb,
                           const int* __restrict__ cand, int* __restrict__ idx_out,
                           float* __restrict__ idx_f) {
    int g = blockIdx.x * blockDim.x + threadIdx.x;
    int n = g >> 4, k = g & 15;
    int b = n >> 11, t = n & 2047;
    const float* xb = in + (long)b * DDIM * TT + t;
    int c = cand[n * 16 + k];
    const float4* e = (const float4*)(cb + (long)c * DDIM);
    double dot = 0.0, nrm = 0.0;
    for (int d4 = 0; d4 < 32; d4++) {
        float4 q = e[d4];
#pragma unroll
        for (int j = 0; j < 4; j++) {
            double xd = (double)xb[(long)(d4 * 4 + j) * TT];
            double f = (double)((const float*)&q)[j];
            dot += xd * f;
            nrm += f * f;
        }
    }
    double sv = dot / fmax(sqrt(nrm), 1e-12);
#pragma unroll
    for (int s = 1; s < 16; s <<= 1) {
        double osv = __shfl_xor(sv, s, 64);
        int oc = __shfl_xor(c, s, 64);
        if (osv > sv || (osv == sv && oc < c)) { sv = osv; c = oc; }
    }
    if (k == 0) {
        idx_out[n] = c;
        idx_f[n] = (float)c;
    }
}

// ---------------------------------------------------------------------------
// k5: out = x + (q - x) + fp64 loss partials (unchanged).
// ---------------------------------------------------------------------------
__global__ void k_out_loss(const float* __restrict__ in, const float* __restrict__ cb,
                           const int* __restrict__ idx, float* __restrict__ out,
                           double* __restrict__ part) {
    __shared__ double sd[256];
    double acc = 0.0;
    for (long e = (long)blockIdx.x * blockDim.x + threadIdx.x; e < ETOT;
         e += (long)gridDim.x * blockDim.x) {
        long t = e & 2047;
        long d = (e >> 11) & 127;
        long b = e >> 18;
        float xv = in[e];
        int n = (int)((b << 11) | t);
        float qv = cb[(long)idx[n] * DDIM + d];
        float diff = qv - xv;
        out[e] = xv + diff;
        acc += (double)diff * (double)diff;
    }
    sd[threadIdx.x] = acc;
    __syncthreads();
    for (int s = 128; s > 0; s >>= 1) {
        if (threadIdx.x < s) sd[threadIdx.x] += sd[threadIdx.x + s];
        __syncthreads();
    }
    if (threadIdx.x == 0) part[blockIdx.x] = sd[0];
}

__global__ void k_loss_final(const double* __restrict__ part, int np,
                             float* __restrict__ loss) {
    __shared__ double sd[256];
    double a = 0.0;
    for (int i = threadIdx.x; i < np; i += 256) a += part[i];
    sd[threadIdx.x] = a;
    __syncthreads();
    for (int s = 128; s > 0; s >>= 1) {
        if (threadIdx.x < s) sd[threadIdx.x] += sd[threadIdx.x + s];
        __syncthreads();
    }
    if (threadIdx.x == 0) {
        float m = (float)(sd[0] / (double)ETOT);
        loss[0] = m + 0.02f * m;
    }
}

// ---------------------------------------------------------------------------
extern "C" void kernel_launch(void* const* d_in, const int* in_sizes, int n_in,
                              void* d_out, int out_size, void* d_ws, size_t ws_size,
                              hipStream_t stream) {
    const float* inputs = (const float*)d_in[0];   // [16,128,2048] fp32
    const float* cb     = (const float*)d_in[1];   // [8192,128]    fp32
    float* outf = (float*)d_out;                   // [loss | out(B,D,T) | idx]

    char* ws = (char*)d_ws;
    _Float16* xh = (_Float16*)ws; ws += (long)NROWS * DDIM * 2;
    _Float16* eh = (_Float16*)ws; ws += (long)KCODES * DDIM * 2;
    int* cand    = (int*)ws;      ws += (long)NROWS * 16 * 4;
    int* idx     = (int*)ws;      ws += (long)NROWS * 4;
    double* part = (double*)ws;   ws += 2048 * 8;

    k_en_prep<<<dim3(2048), dim3(256), 0, stream>>>(cb, eh);
    k_x_prep<<<dim3(1024), dim3(256), 0, stream>>>(inputs, xh);
    k_main<<<dim3(1024), dim3(256), 25600, stream>>>(xh, eh, cand);
    k_refine16<<<dim3(2048), dim3(256), 0, stream>>>(inputs, cb, cand, idx,
                                                     outf + 1 + (long)ETOT);
    k_out_loss<<<dim3(2048), dim3(256), 0, stream>>>(inputs, cb, idx, outf + 1, part);
    k_loss_final<<<dim3(1), dim3(256), 0, stream>>>(part, 2048, outf);
}

// Round 15
// 160.975 us; speedup vs baseline: 2.2638x; 1.1659x over previous
//
#include <hip/hip_runtime.h>
#include <hip/hip_bf16.h>

#define NROWS 32768
#define KCODES 8192
#define DDIM 128
#define TT 2048
#define ETOT 4194304  // 16*128*2048

typedef __attribute__((ext_vector_type(8))) _Float16 f16x8;
typedef __attribute__((ext_vector_type(4))) float f32x4;

// pack: (v & ~0x1FFF) | p, p in [0,8191] -> single v_and_or_b32.
__device__ __forceinline__ float pk(float v, int p) {
    return __int_as_float((__float_as_int(v) & 0xFFFFE000) | p);
}

__device__ __forceinline__ void async16(char* lds_uniform, const char* g_perlane) {
    __builtin_amdgcn_global_load_lds(
        (const __attribute__((address_space(1))) unsigned int*)g_perlane,
        (__attribute__((address_space(3))) unsigned int*)lds_uniform,
        16, 0, 0);
}

#define SYNC_MAIN asm volatile("s_waitcnt vmcnt(1) lgkmcnt(0)\n\ts_barrier" ::: "memory")
#define SYNC_LAST asm volatile("s_waitcnt vmcnt(0) lgkmcnt(0)\n\ts_barrier" ::: "memory")

// ---------------------------------------------------------------------------
// k1: normalize codebook rows, fp32 -> fp16, MFMA A-fragment order per
//     16-code tile (4KB each).
// ---------------------------------------------------------------------------
__global__ void k_en_prep(const float* __restrict__ cb,
                          _Float16* __restrict__ eh) {
    int w = (blockIdx.x * blockDim.x + threadIdx.x) >> 6;  // code id
    int l = threadIdx.x & 63;
    if (w >= KCODES) return;
    const float* row = cb + (long)w * DDIM;
    float v0 = row[l], v1 = row[l + 64];
    float ss = v0 * v0 + v1 * v1;
#pragma unroll
    for (int s = 1; s < 64; s <<= 1) ss += __shfl_xor(ss, s, 64);
    float inv = 1.0f / fmaxf(sqrtf(ss), 1e-12f);
    int tile = w >> 4, c = w & 15;
#pragma unroll
    for (int e = 0; e < 2; e++) {
        int d = l + e * 64;
        float v = (e ? v1 : v0) * inv;
        int ks = d >> 5, kq = (d >> 3) & 3, dr = d & 7;
        long off = (long)tile * 2048 + ks * 512 + (kq * 16 + c) * 8 + dr;
        eh[off] = (_Float16)v;
    }
}

// ---------------------------------------------------------------------------
// k2: transpose inputs [B,D,T] -> xh [N=B*T, D] row-major fp16.
// ---------------------------------------------------------------------------
__global__ void k_x_prep(const float* __restrict__ in,
                         _Float16* __restrict__ xh) {
    __shared__ float tb[64][65];
    int bid = blockIdx.x;
    int tt0 = (bid & 31) * 64;
    int dd0 = ((bid >> 5) & 1) * 64;
    int b = bid >> 6;
    const float* base = in + (long)b * DDIM * TT;
    int tl = threadIdx.x & 63;
    int dg = threadIdx.x >> 6;
#pragma unroll
    for (int i = 0; i < 16; i++) {
        int dd = dg + i * 4;
        tb[dd][tl] = base[(long)(dd0 + dd) * TT + tt0 + tl];
    }
    __syncthreads();
    int dl = threadIdx.x & 63;
    int tg = threadIdx.x >> 6;
#pragma unroll
    for (int i = 0; i < 16; i++) {
        int t = tg + i * 4;
        long n = (long)b * TT + tt0 + t;
        xh[n * DDIM + dd0 + dl] = (_Float16)tb[dl][t];
    }
}

// ---------------------------------------------------------------------------
// helpers for k_main's 2-phase pipeline (static acc naming, rule #20)
// ---------------------------------------------------------------------------
__device__ __forceinline__ void mfma4(const char* buf, int l,
                                      const f16x8 (&bx)[4][4], f32x4 (&acc)[4]) {
    const f32x4 Z = {0.f, 0.f, 0.f, 0.f};
    f16x8 ah[4];
#pragma unroll
    for (int ks = 0; ks < 4; ks++)
        ah[ks] = *(const f16x8*)(buf + ks * 1024 + l * 16);
    __builtin_amdgcn_s_setprio(1);
#pragma unroll
    for (int nf = 0; nf < 4; nf++) {
        f32x4 a = __builtin_amdgcn_mfma_f32_16x16x32_f16(ah[0], bx[nf][0], Z, 0, 0, 0);
        a = __builtin_amdgcn_mfma_f32_16x16x32_f16(ah[1], bx[nf][1], a, 0, 0, 0);
        a = __builtin_amdgcn_mfma_f32_16x16x32_f16(ah[2], bx[nf][2], a, 0, 0, 0);
        acc[nf] = __builtin_amdgcn_mfma_f32_16x16x32_f16(ah[3], bx[nf][3], a, 0, 0, 0);
    }
    __builtin_amdgcn_s_setprio(0);
}

// {t1,t2,u1}: exact top-2 per eighth (cross-quad top-2 via t1/t2, same-quad
// second via u1; 16-cand fp64 refine unchanged).
__device__ __forceinline__ void sel4(const f32x4 (&acc)[4], int PP,
                                     float (&t1)[4], float (&t2)[4], float (&u1)[4]) {
#pragma unroll
    for (int nf = 0; nf < 4; nf++) {
        f32x4 a = acc[nf];
        float s0 = pk(a[0], PP),     s1 = pk(a[1], PP - 1);
        float s2 = pk(a[2], PP - 2), s3 = pk(a[3], PP - 3);
        float h01 = fmaxf(s0, s1), l01 = fminf(s0, s1);
        float h23 = fmaxf(s2, s3), l23 = fminf(s2, s3);
        float m1 = fmaxf(h01, h23);                          // quad max
        float m2 = fmaxf(fminf(h01, h23), fmaxf(l01, l23));  // quad 2nd
        float n1 = fminf(t1[nf], m1); t1[nf] = fmaxf(t1[nf], m1);
        t2[nf] = fmaxf(t2[nf], n1);
        u1[nf] = fmaxf(u1[nf], m2);
    }
}

// ---------------------------------------------------------------------------
// k3 v14: r13's pipeline at 3 waves/SIMD. r14's version spilled: accA+accB+
// bx = ~139 regs > 128 (the 4-waves/SIMD budget) -> WRITE_SIZE 23.5MB of
// scratch. __launch_bounds__(256,3) -> 170 regs/wave: fits, no spill.
// MFMA(t)->accB issues, sel(accA = tile t-1) fills the MFMA shadow.
// ---------------------------------------------------------------------------
__global__ __launch_bounds__(256, 3) void k_main(const _Float16* __restrict__ xh,
                                                 const _Float16* __restrict__ eh,
                                                 int* __restrict__ cand) {
    extern __shared__ char lds[];
    const int tid = threadIdx.x;
    const int l = tid & 63;
    const int w = tid >> 6;
    const int e8 = blockIdx.x & 7;
    const int rb = blockIdx.x >> 3;
    const int col = l & 15, kq = l >> 4;
    const long rbase = (long)rb * 256;

    f16x8 bx[4][4];
#pragma unroll
    for (int nf = 0; nf < 4; nf++) {
        long n = rbase + w * 64 + nf * 16 + col;
#pragma unroll
        for (int ks = 0; ks < 4; ks++)
            bx[nf][ks] = *(const f16x8*)(xh + n * DDIM + ks * 32 + kq * 8);
    }

    const float NEG = __int_as_float(0xFF800000);
    float t1[4], t2[4], u1[4];
#pragma unroll
    for (int i = 0; i < 4; i++) { t1[i] = t2[i] = u1[i] = NEG; }

    int P = 8191 - (e8 * 1024 + kq * 4);

    const char* gsrc = (const char*)eh + (long)e8 * 262144 + w * 1024 + l * 16;
    char* b0 = lds;
    char* b1 = lds + 4096;
    char* b2 = lds + 8192;

    // prologue: stage tiles 0,1; tile 0 -> accA
    async16(b0 + w * 1024, gsrc);
    async16(b1 + w * 1024, gsrc + 4096);

    f32x4 accA[4], accB[4];
    int PA, PB;

    SYNC_MAIN;                                   // tile 0 landed (1 in flight)
    async16(b2 + w * 1024, gsrc + 2 * 4096);     // stage tile 2
    mfma4(b0, l, bx, accA); PA = P; P -= 16;
    { char* tp = b0; b0 = b1; b1 = b2; b2 = tp; }

    for (int u = 0; u < 31; ++u) {
        // tile 2u+1 -> accB ; sel(accA) in its MFMA shadow
        SYNC_MAIN;
        async16(b2 + w * 1024, gsrc + (2 * u + 3) * 4096);
        mfma4(b0, l, bx, accB); PB = P; P -= 16;
        sel4(accA, PA, t1, t2, u1);
        { char* tp = b0; b0 = b1; b1 = b2; b2 = tp; }

        // tile 2u+2 -> accA ; sel(accB)
        SYNC_MAIN;
        if (u != 30) async16(b2 + w * 1024, gsrc + (2 * u + 4) * 4096);
        mfma4(b0, l, bx, accA); PA = P; P -= 16;
        sel4(accB, PB, t1, t2, u1);
        { char* tp = b0; b0 = b1; b1 = b2; b2 = tp; }
    }
    // tile 63 -> accB ; drain
    SYNC_LAST;
    mfma4(b0, l, bx, accB); PB = P;
    sel4(accA, PA, t1, t2, u1);
    sel4(accB, PB, t1, t2, u1);

    // merge: 12 entries per row (4 kq x {t1,t2,u1}) -> top-2/eighth
    float* mrg = (float*)(lds + 12288);  // [256 rows][13]
#pragma unroll
    for (int nf = 0; nf < 4; nf++) {
        int row = w * 64 + nf * 16 + col;
        int e = kq * 3;
        mrg[row * 13 + e + 0] = t1[nf];
        mrg[row * 13 + e + 1] = t2[nf];
        mrg[row * 13 + e + 2] = u1[nf];
    }
    __syncthreads();
    {
        float s1 = NEG, s2 = NEG;
#pragma unroll 4
        for (int e = 0; e < 12; e++) {
            float v = mrg[tid * 13 + e];
            float a1 = fminf(s1, v); s1 = fmaxf(s1, v);
            s2 = fmaxf(s2, a1);
        }
        long n = rbase + tid;
        int* cp = cand + n * 16 + e8 * 2;
        cp[0] = 8191 - (__float_as_int(s1) & 0x1FFF);
        cp[1] = 8191 - (__float_as_int(s2) & 0x1FFF);
    }
}

// ---------------------------------------------------------------------------
// k4 v4: lane-per-(row,candidate) fp64 refine (unchanged).
// ---------------------------------------------------------------------------
__global__ void k_refine16(const float* __restrict__ in, const float* __restrict__ cb,
                           const int* __restrict__ cand, int* __restrict__ idx_out,
                           float* __restrict__ idx_f) {
    int g = blockIdx.x * blockDim.x + threadIdx.x;
    int n = g >> 4, k = g & 15;
    int b = n >> 11, t = n & 2047;
    const float* xb = in + (long)b * DDIM * TT + t;
    int c = cand[n * 16 + k];
    const float4* e = (const float4*)(cb + (long)c * DDIM);
    double dot = 0.0, nrm = 0.0;
    for (int d4 = 0; d4 < 32; d4++) {
        float4 q = e[d4];
#pragma unroll
        for (int j = 0; j < 4; j++) {
            double xd = (double)xb[(long)(d4 * 4 + j) * TT];
            double f = (double)((const float*)&q)[j];
            dot += xd * f;
            nrm += f * f;
        }
    }
    double sv = dot / fmax(sqrt(nrm), 1e-12);
#pragma unroll
    for (int s = 1; s < 16; s <<= 1) {
        double osv = __shfl_xor(sv, s, 64);
        int oc = __shfl_xor(c, s, 64);
        if (osv > sv || (osv == sv && oc < c)) { sv = osv; c = oc; }
    }
    if (k == 0) {
        idx_out[n] = c;
        idx_f[n] = (float)c;
    }
}

// ---------------------------------------------------------------------------
// k5: out = x + (q - x) + fp64 loss partials (unchanged).
// ---------------------------------------------------------------------------
__global__ void k_out_loss(const float* __restrict__ in, const float* __restrict__ cb,
                           const int* __restrict__ idx, float* __restrict__ out,
                           double* __restrict__ part) {
    __shared__ double sd[256];
    double acc = 0.0;
    for (long e = (long)blockIdx.x * blockDim.x + threadIdx.x; e < ETOT;
         e += (long)gridDim.x * blockDim.x) {
        long t = e & 2047;
        long d = (e >> 11) & 127;
        long b = e >> 18;
        float xv = in[e];
        int n = (int)((b << 11) | t);
        float qv = cb[(long)idx[n] * DDIM + d];
        float diff = qv - xv;
        out[e] = xv + diff;
        acc += (double)diff * (double)diff;
    }
    sd[threadIdx.x] = acc;
    __syncthreads();
    for (int s = 128; s > 0; s >>= 1) {
        if (threadIdx.x < s) sd[threadIdx.x] += sd[threadIdx.x + s];
        __syncthreads();
    }
    if (threadIdx.x == 0) part[blockIdx.x] = sd[0];
}

__global__ void k_loss_final(const double* __restrict__ part, int np,
                             float* __restrict__ loss) {
    __shared__ double sd[256];
    double a = 0.0;
    for (int i = threadIdx.x; i < np; i += 256) a += part[i];
    sd[threadIdx.x] = a;
    __syncthreads();
    for (int s = 128; s > 0; s >>= 1) {
        if (threadIdx.x < s) sd[threadIdx.x] += sd[threadIdx.x + s];
        __syncthreads();
    }
    if (threadIdx.x == 0) {
        float m = (float)(sd[0] / (double)ETOT);
        loss[0] = m + 0.02f * m;
    }
}

// ---------------------------------------------------------------------------
extern "C" void kernel_launch(void* const* d_in, const int* in_sizes, int n_in,
                              void* d_out, int out_size, void* d_ws, size_t ws_size,
                              hipStream_t stream) {
    const float* inputs = (const float*)d_in[0];   // [16,128,2048] fp32
    const float* cb     = (const float*)d_in[1];   // [8192,128]    fp32
    float* outf = (float*)d_out;                   // [loss | out(B,D,T) | idx]

    char* ws = (char*)d_ws;
    _Float16* xh = (_Float16*)ws; ws += (long)NROWS * DDIM * 2;
    _Float16* eh = (_Float16*)ws; ws += (long)KCODES * DDIM * 2;
    int* cand    = (int*)ws;      ws += (long)NROWS * 16 * 4;
    int* idx     = (int*)ws;      ws += (long)NROWS * 4;
    double* part = (double*)ws;   ws += 2048 * 8;

    k_en_prep<<<dim3(2048), dim3(256), 0, stream>>>(cb, eh);
    k_x_prep<<<dim3(1024), dim3(256), 0, stream>>>(inputs, xh);
    k_main<<<dim3(1024), dim3(256), 25600, stream>>>(xh, eh, cand);
    k_refine16<<<dim3(2048), dim3(256), 0, stream>>>(inputs, cb, cand, idx,
                                                     outf + 1 + (long)ETOT);
    k_out_loss<<<dim3(2048), dim3(256), 0, stream>>>(inputs, cb, idx, outf + 1, part);
    k_loss_final<<<dim3(1), dim3(256), 0, stream>>>(part, 2048, outf);
}

// Round 16
// 138.185 us; speedup vs baseline: 2.6372x; 1.1649x over previous
//
#include <hip/hip_runtime.h>
#include <hip/hip_bf16.h>

#define NROWS 32768
#define KCODES 8192
#define DDIM 128
#define TT 2048
#define ETOT 4194304  // 16*128*2048

typedef __attribute__((ext_vector_type(8))) _Float16 f16x8;
typedef __attribute__((ext_vector_type(4))) float f32x4;

// pack: (v & ~0x1FFF) | p, p in [0,8191] -> single v_and_or_b32.
__device__ __forceinline__ float pk(float v, int p) {
    return __int_as_float((__float_as_int(v) & 0xFFFFE000) | p);
}

__device__ __forceinline__ void async16(char* lds_uniform, const char* g_perlane) {
    __builtin_amdgcn_global_load_lds(
        (const __attribute__((address_space(1))) unsigned int*)g_perlane,
        (__attribute__((address_space(3))) unsigned int*)lds_uniform,
        16, 0, 0);
}

#define SYNC2 asm volatile("s_waitcnt vmcnt(2) lgkmcnt(0)\n\ts_barrier" ::: "memory")
#define SYNC0 asm volatile("s_waitcnt vmcnt(0) lgkmcnt(0)\n\ts_barrier" ::: "memory")

// ---------------------------------------------------------------------------
// k1: normalize codebook rows, fp32 -> fp16, MFMA A-fragment order per
//     16-code tile (4KB each).
// ---------------------------------------------------------------------------
__global__ void k_en_prep(const float* __restrict__ cb,
                          _Float16* __restrict__ eh) {
    int w = (blockIdx.x * blockDim.x + threadIdx.x) >> 6;  // code id
    int l = threadIdx.x & 63;
    if (w >= KCODES) return;
    const float* row = cb + (long)w * DDIM;
    float v0 = row[l], v1 = row[l + 64];
    float ss = v0 * v0 + v1 * v1;
#pragma unroll
    for (int s = 1; s < 64; s <<= 1) ss += __shfl_xor(ss, s, 64);
    float inv = 1.0f / fmaxf(sqrtf(ss), 1e-12f);
    int tile = w >> 4, c = w & 15;
#pragma unroll
    for (int e = 0; e < 2; e++) {
        int d = l + e * 64;
        float v = (e ? v1 : v0) * inv;
        int ks = d >> 5, kq = (d >> 3) & 3, dr = d & 7;
        long off = (long)tile * 2048 + ks * 512 + (kq * 16 + c) * 8 + dr;
        eh[off] = (_Float16)v;
    }
}

// ---------------------------------------------------------------------------
// k2: transpose inputs [B,D,T] -> xh [N=B*T, D] row-major fp16.
// ---------------------------------------------------------------------------
__global__ void k_x_prep(const float* __restrict__ in,
                         _Float16* __restrict__ xh) {
    __shared__ float tb[64][65];
    int bid = blockIdx.x;
    int tt0 = (bid & 31) * 64;
    int dd0 = ((bid >> 5) & 1) * 64;
    int b = bid >> 6;
    const float* base = in + (long)b * DDIM * TT;
    int tl = threadIdx.x & 63;
    int dg = threadIdx.x >> 6;
#pragma unroll
    for (int i = 0; i < 16; i++) {
        int dd = dg + i * 4;
        tb[dd][tl] = base[(long)(dd0 + dd) * TT + tt0 + tl];
    }
    __syncthreads();
    int dl = threadIdx.x & 63;
    int tg = threadIdx.x >> 6;
#pragma unroll
    for (int i = 0; i < 16; i++) {
        int t = tg + i * 4;
        long n = (long)b * TT + tt0 + t;
        xh[n * DDIM + dd0 + dl] = (_Float16)tb[dl][t];
    }
}

// ---------------------------------------------------------------------------
// helpers (static acc naming, rule #20)
// ---------------------------------------------------------------------------
__device__ __forceinline__ void mfma4(const char* buf, int l,
                                      const f16x8 (&bx)[4][4], f32x4 (&acc)[4]) {
    const f32x4 Z = {0.f, 0.f, 0.f, 0.f};
    f16x8 ah[4];
#pragma unroll
    for (int ks = 0; ks < 4; ks++)
        ah[ks] = *(const f16x8*)(buf + ks * 1024 + l * 16);
    __builtin_amdgcn_s_setprio(1);
#pragma unroll
    for (int nf = 0; nf < 4; nf++) {
        f32x4 a = __builtin_amdgcn_mfma_f32_16x16x32_f16(ah[0], bx[nf][0], Z, 0, 0, 0);
        a = __builtin_amdgcn_mfma_f32_16x16x32_f16(ah[1], bx[nf][1], a, 0, 0, 0);
        a = __builtin_amdgcn_mfma_f32_16x16x32_f16(ah[2], bx[nf][2], a, 0, 0, 0);
        acc[nf] = __builtin_amdgcn_mfma_f32_16x16x32_f16(ah[3], bx[nf][3], a, 0, 0, 0);
    }
    __builtin_amdgcn_s_setprio(0);
}

// {t1,t2,u1}: exact top-2 per eighth (cross-quad via t1/t2, same-quad 2nd
// via u1); feeds the 16-candidate exact fp64 refine.
__device__ __forceinline__ void sel4(const f32x4 (&acc)[4], int PP,
                                     float (&t1)[4], float (&t2)[4], float (&u1)[4]) {
#pragma unroll
    for (int nf = 0; nf < 4; nf++) {
        f32x4 a = acc[nf];
        float s0 = pk(a[0], PP),     s1 = pk(a[1], PP - 1);
        float s2 = pk(a[2], PP - 2), s3 = pk(a[3], PP - 3);
        float h01 = fmaxf(s0, s1), l01 = fminf(s0, s1);
        float h23 = fmaxf(s2, s3), l23 = fminf(s2, s3);
        float m1 = fmaxf(h01, h23);                          // quad max
        float m2 = fmaxf(fminf(h01, h23), fmaxf(l01, l23));  // quad 2nd
        float n1 = fminf(t1[nf], m1); t1[nf] = fmaxf(t1[nf], m1);
        t2[nf] = fmaxf(t2[nf], n1);
        u1[nf] = fmaxf(u1[nf], m2);
    }
}

// ---------------------------------------------------------------------------
// k3 v15: r15's sel-shadow pipeline with 2-TILE PHASES (32 barriers, not 64;
// 32-MFMA bursts). 3 x 8KB buffers, counted vmcnt(2). Per phase:
// SYNC2 -> stage(p+2) -> mfma(t0->accA) -> sel(prev accB) -> mfma(t1->accB)
// -> sel(accA). Each sel is >=16 MFMAs behind its producing chain.
// ---------------------------------------------------------------------------
__global__ __launch_bounds__(256, 3) void k_main(const _Float16* __restrict__ xh,
                                                 const _Float16* __restrict__ eh,
                                                 int* __restrict__ cand) {
    extern __shared__ char lds[];
    const int tid = threadIdx.x;
    const int l = tid & 63;
    const int w = tid >> 6;
    const int e8 = blockIdx.x & 7;
    const int rb = blockIdx.x >> 3;
    const int col = l & 15, kq = l >> 4;
    const long rbase = (long)rb * 256;

    f16x8 bx[4][4];
#pragma unroll
    for (int nf = 0; nf < 4; nf++) {
        long n = rbase + w * 64 + nf * 16 + col;
#pragma unroll
        for (int ks = 0; ks < 4; ks++)
            bx[nf][ks] = *(const f16x8*)(xh + n * DDIM + ks * 32 + kq * 8);
    }

    const float NEG = __int_as_float(0xFF800000);
    float t1[4], t2[4], u1[4];
#pragma unroll
    for (int i = 0; i < 4; i++) { t1[i] = t2[i] = u1[i] = NEG; }

    int P = 8191 - (e8 * 1024 + kq * 4);

    const char* gsrc = (const char*)eh + (long)e8 * 262144 + w * 1024 + l * 16;
    char* b0 = lds;
    char* b1 = lds + 8192;
    char* b2 = lds + 16384;

    // prologue: stage phases 0,1 (2 tiles = 2 async16 each)
    async16(b0 + w * 1024, gsrc);
    async16(b0 + 4096 + w * 1024, gsrc + 4096);
    async16(b1 + w * 1024, gsrc + 8192);
    async16(b1 + 4096 + w * 1024, gsrc + 12288);

    f32x4 accA[4], accB[4];
    int PA, PB;

    // phase 0 (peeled: no prev accB)
    SYNC2;
    async16(b2 + w * 1024, gsrc + 2 * 8192);
    async16(b2 + 4096 + w * 1024, gsrc + 2 * 8192 + 4096);
    mfma4(b0, l, bx, accA); PA = P; P -= 16;
    mfma4(b0 + 4096, l, bx, accB); PB = P; P -= 16;
    sel4(accA, PA, t1, t2, u1);
    { char* tp = b0; b0 = b1; b1 = b2; b2 = tp; }

    for (int p = 1; p <= 30; ++p) {
        SYNC2;
        if (p < 30) {
            async16(b2 + w * 1024, gsrc + (long)(p + 2) * 8192);
            async16(b2 + 4096 + w * 1024, gsrc + (long)(p + 2) * 8192 + 4096);
        }
        mfma4(b0, l, bx, accA); PA = P; P -= 16;
        sel4(accB, PB, t1, t2, u1);          // prev phase's tile 1
        mfma4(b0 + 4096, l, bx, accB); PB = P; P -= 16;
        sel4(accA, PA, t1, t2, u1);
        { char* tp = b0; b0 = b1; b1 = b2; b2 = tp; }
    }
    // phase 31 (peeled: final drain)
    SYNC0;
    mfma4(b0, l, bx, accA); PA = P; P -= 16;
    sel4(accB, PB, t1, t2, u1);
    mfma4(b0 + 4096, l, bx, accB); PB = P;
    sel4(accA, PA, t1, t2, u1);
    sel4(accB, PB, t1, t2, u1);

    __syncthreads();  // all staging/reads done; reuse LDS base for merge
    float* mrg = (float*)lds;  // [256 rows][13]
#pragma unroll
    for (int nf = 0; nf < 4; nf++) {
        int row = w * 64 + nf * 16 + col;
        int e = kq * 3;
        mrg[row * 13 + e + 0] = t1[nf];
        mrg[row * 13 + e + 1] = t2[nf];
        mrg[row * 13 + e + 2] = u1[nf];
    }
    __syncthreads();
    {
        float s1 = NEG, s2 = NEG;
#pragma unroll 4
        for (int e = 0; e < 12; e++) {
            float v = mrg[tid * 13 + e];
            float a1 = fminf(s1, v); s1 = fmaxf(s1, v);
            s2 = fmaxf(s2, a1);
        }
        long n = rbase + tid;
        int* cp = cand + n * 16 + e8 * 2;
        cp[0] = 8191 - (__float_as_int(s1) & 0x1FFF);
        cp[1] = 8191 - (__float_as_int(s2) & 0x1FFF);
    }
}

// ---------------------------------------------------------------------------
// k4 v5 (FUSED refine + out + loss): 2048 blocks x 256 thr; block = 16 rows
// (same b, consecutive t). Stage x-slab in[b, :, t0:t0+16] into LDS ONCE
// (coalesced; kills refine16's 16x strided re-read). 16 lanes/row score 16
// candidates in fp64 from LDS (broadcast), shuffle-reduce exact; then the
// block writes out = x+(q-x) (coalesced) + fp64 loss partials.
// ---------------------------------------------------------------------------
__global__ void k_rf(const float* __restrict__ in, const float* __restrict__ cb,
                     const int* __restrict__ cand, float* __restrict__ out,
                     float* __restrict__ idx_f, double* __restrict__ part) {
    __shared__ float xs[16][132];   // [t-local][d], pad 4
    __shared__ int sbi[16];
    __shared__ double sd[256];
    const int tid = threadIdx.x;
    const int n0 = blockIdx.x * 16;
    const int b = n0 >> 11, t0 = n0 & 2047;

    // stage x slab: thread (d = tid>>1, h = tid&1) loads 8 consecutive t
    {
        int d = tid >> 1, h = tid & 1;
        const float* src = in + ((long)b * DDIM + d) * TT + t0 + h * 8;
        float4 v0 = *(const float4*)src;
        float4 v1 = *(const float4*)(src + 4);
#pragma unroll
        for (int j = 0; j < 4; j++) {
            xs[h * 8 + j][d] = ((const float*)&v0)[j];
            xs[h * 8 + 4 + j][d] = ((const float*)&v1)[j];
        }
    }
    __syncthreads();

    // refine: r = tid>>4 covers rows 0..15, k = tid&15 the candidate
    {
        int r = tid >> 4, k = tid & 15;
        int n = n0 + r;
        int c = cand[n * 16 + k];
        const float4* e = (const float4*)(cb + (long)c * DDIM);
        double dot = 0.0, nrm = 0.0;
        for (int d4 = 0; d4 < 32; d4++) {
            float4 q = e[d4];
#pragma unroll
            for (int j = 0; j < 4; j++) {
                double xd = (double)xs[r][d4 * 4 + j];
                double f = (double)((const float*)&q)[j];
                dot += xd * f;
                nrm += f * f;
            }
        }
        double sv = dot / fmax(sqrt(nrm), 1e-12);
#pragma unroll
        for (int s = 1; s < 16; s <<= 1) {
            double osv = __shfl_xor(sv, s, 64);
            int oc = __shfl_xor(c, s, 64);
            if (osv > sv || (osv == sv && oc < c)) { sv = osv; c = oc; }
        }
        if (k == 0) {
            sbi[r] = c;
            idx_f[n] = (float)c;
        }
    }
    __syncthreads();

    // epilogue: out = x + (q - x) + loss partials (same (d,h) mapping)
    {
        int d = tid >> 1, h = tid & 1;
        float* ob = out + ((long)b * DDIM + d) * TT + t0 + h * 8;
        double acc = 0.0;
        float ov[8];
#pragma unroll
        for (int j = 0; j < 8; j++) {
            int rr = h * 8 + j;
            float xv = xs[rr][d];
            float qv = cb[(long)sbi[rr] * DDIM + d];
            float diff = qv - xv;
            ov[j] = xv + diff;
            acc += (double)diff * (double)diff;
        }
        *(float4*)ob = make_float4(ov[0], ov[1], ov[2], ov[3]);
        *(float4*)(ob + 4) = make_float4(ov[4], ov[5], ov[6], ov[7]);
        sd[tid] = acc;
    }
    __syncthreads();
    for (int s = 128; s > 0; s >>= 1) {
        if (tid < s) sd[tid] += sd[tid + s];
        __syncthreads();
    }
    if (tid == 0) part[blockIdx.x] = sd[0];
}

__global__ void k_loss_final(const double* __restrict__ part, int np,
                             float* __restrict__ loss) {
    __shared__ double sd[256];
    double a = 0.0;
    for (int i = threadIdx.x; i < np; i += 256) a += part[i];
    sd[threadIdx.x] = a;
    __syncthreads();
    for (int s = 128; s > 0; s >>= 1) {
        if (threadIdx.x < s) sd[threadIdx.x] += sd[threadIdx.x + s];
        __syncthreads();
    }
    if (threadIdx.x == 0) {
        float m = (float)(sd[0] / (double)ETOT);
        loss[0] = m + 0.02f * m;
    }
}

// ---------------------------------------------------------------------------
extern "C" void kernel_launch(void* const* d_in, const int* in_sizes, int n_in,
                              void* d_out, int out_size, void* d_ws, size_t ws_size,
                              hipStream_t stream) {
    const float* inputs = (const float*)d_in[0];   // [16,128,2048] fp32
    const float* cb     = (const float*)d_in[1];   // [8192,128]    fp32
    float* outf = (float*)d_out;                   // [loss | out(B,D,T) | idx]

    char* ws = (char*)d_ws;
    _Float16* xh = (_Float16*)ws; ws += (long)NROWS * DDIM * 2;
    _Float16* eh = (_Float16*)ws; ws += (long)KCODES * DDIM * 2;
    int* cand    = (int*)ws;      ws += (long)NROWS * 16 * 4;
    double* part = (double*)ws;   ws += 2048 * 8;

    k_en_prep<<<dim3(2048), dim3(256), 0, stream>>>(cb, eh);
    k_x_prep<<<dim3(1024), dim3(256), 0, stream>>>(inputs, xh);
    k_main<<<dim3(1024), dim3(256), 24576, stream>>>(xh, eh, cand);
    k_rf<<<dim3(2048), dim3(256), 0, stream>>>(inputs, cb, cand, outf + 1,
                                               outf + 1 + (long)ETOT, part);
    k_loss_final<<<dim3(1), dim3(256), 0, stream>>>(part, 2048, outf);
}